// Round 10
// baseline (430.390 us; speedup 1.0000x reference)
//
#include <hip/hip_runtime.h>
#include <stdint.h>

#define B_ 4
#define NH_ 32
#define SQ_ 512
#define HD_ 128
#define MLEN_ 3584
#define KT_ 4096           // MLEN_ + SQ_
#define QB_ 128
#define KB_ 32
#define NTILE_ 128         // KT_ / KB_
#define MEMTILES_ 112      // MLEN_ / KB_

typedef float f32x4 __attribute__((ext_vector_type(4)));
typedef short s16x8 __attribute__((ext_vector_type(8)));

__device__ __forceinline__ f32x4 MFMA16(s16x8 a, s16x8 b, f32x4 c) {
    return __builtin_amdgcn_mfma_f32_16x16x32_bf16(a, b, c, 0, 0, 0);
}

// Async global->LDS, 16B per lane. Dest = wave-uniform base + lane*16 (linear).
__device__ __forceinline__ void gload16(const float* g, void* l) {
    __builtin_amdgcn_global_load_lds(
        (const __attribute__((address_space(1))) void*)g,
        (__attribute__((address_space(3))) void*)l, 16, 0, 0);
}

__device__ __forceinline__ s16x8 cvt8(float4 a, float4 b) {
    union { s16x8 v; __bf16 h[8]; } u;
    u.h[0] = (__bf16)a.x; u.h[1] = (__bf16)a.y;
    u.h[2] = (__bf16)a.z; u.h[3] = (__bf16)a.w;
    u.h[4] = (__bf16)b.x; u.h[5] = (__bf16)b.y;
    u.h[6] = (__bf16)b.z; u.h[7] = (__bf16)b.w;
    return u.v;
}

// 8 waves x 16 q-rows, KB=32. LDS: f32 staging dbuf (2x32KB, linear, filled by
// global_load_lds with ZERO registers) + bf16 K/V^T (16KB, swizzled).
// 80KB/block -> exactly 2 blocks/CU. Per tile: compute(t) runs while
// async(t+1..t+2) fly; __syncthreads' vmcnt(0) drain IS the arrival wait.
__launch_bounds__(512)
__global__ void attn_kernel(const float* __restrict__ q, const float* __restrict__ k,
                            const float* __restrict__ v, const float* __restrict__ mask,
                            const float* __restrict__ mem, float* __restrict__ ctx)
{
    __shared__ float  F32K[2][KB_ * HD_];   // 2 x 16 KB, linear [row][hd]
    __shared__ float  F32V[2][KB_ * HD_];   // 2 x 16 KB, linear [row][hd]
    __shared__ __bf16 Kb[KB_ * HD_];        // 8 KB, swizzled rows
    __shared__ __bf16 Vtb[HD_ * KB_];       // 8 KB, transposed + swizzled

    const int tid  = threadIdx.x;
    const int lane = tid & 63;
    const int w    = tid >> 6;              // 0..7
    const int l15  = lane & 15;
    const int l4   = lane >> 4;             // 0..3
    const int r2   = lane >> 5;             // async: row within segment
    const int c32  = lane & 31;             // async: 16B chunk within row

    const int qt   = blockIdx.x >> 7;
    const int pair = blockIdx.x & 127;
    const int b    = pair >> 5;
    const int h    = pair & 31;
    const int q0   = qt * QB_;

    // ---- Q fragments (B-operand; lane l15 = q-row, k-elem = l4*8+j = d) ----
    const float scale = 0.088388347648318447f;   // 1/sqrt(128)
    s16x8 qf[4];
    {
        const float* qbase = q + (((size_t)(b * NH_ + h)) * SQ_ + q0 + w * 16 + l15) * HD_;
        #pragma unroll
        for (int kc = 0; kc < 4; ++kc) {
            const float* p = qbase + kc * 32 + l4 * 8;
            float4 a = *(const float4*)p;
            float4 c = *(const float4*)(p + 4);
            a.x *= scale; a.y *= scale; a.z *= scale; a.w *= scale;
            c.x *= scale; c.y *= scale; c.z *= scale; c.w *= scale;
            qf[kc] = cvt8(a, c);
        }
    }

    f32x4 acc[8];
    #pragma unroll
    for (int n = 0; n < 8; ++n) acc[n] = (f32x4){0.f, 0.f, 0.f, 0.f};

    float mrun = -3.0e38f, lrun = 0.f;      // per-lane stats for q = w*16 + l15

    const float* maskrow = mask + ((size_t)b * SQ_ + q0 + w * 16 + l15) * KT_;

    // ---------- async stage of tile tt into staging buffer p ----------
    // K tile = 32x128 f32 = 16KB = 16 segments x 1KB; wave w issues segs 2w,2w+1.
    // Per segment: rows seg*2 + (lane>>5), cols (lane&31)*4..+3 (16B/lane).
#define ISSUE_TILE(tt, p)                                                              \
    {                                                                                  \
        const int _kv0 = (tt) * KB_;                                                   \
        const float *_sk, *_sv; int _rs;                                               \
        if ((tt) < MEMTILES_) {                                                        \
            const float* _m = mem + ((size_t)b * MLEN_ + _kv0) * (2 * NH_ * HD_) + h * HD_; \
            _sk = _m; _sv = _m + NH_ * HD_; _rs = 2 * NH_ * HD_;                       \
        } else {                                                                       \
            size_t _o = (((size_t)b * NH_ + h) * SQ_ + (_kv0 - MLEN_)) * HD_;          \
            _sk = k + _o; _sv = v + _o; _rs = HD_;                                     \
        }                                                                              \
        _Pragma("unroll")                                                              \
        for (int _s = 0; _s < 2; ++_s) {                                               \
            int _seg = w * 2 + _s;                                                     \
            int _row = _seg * 2 + r2;                                                  \
            gload16(_sk + (size_t)_row * _rs + c32 * 4, (char*)F32K[p] + _seg * 1024); \
            gload16(_sv + (size_t)_row * _rs + c32 * 4, (char*)F32V[p] + _seg * 1024); \
        }                                                                              \
    }

    // ---------- cvt pass: f32 staging -> swizzled bf16 K / V^T ----------
#define CVT_TILE(p)                                                                    \
    {                                                                                  \
        int _kr = tid >> 4, _kc = tid & 15;                                            \
        const float* _s = &F32K[p][_kr * HD_ + _kc * 8];                               \
        float4 _a = *(const float4*)_s;                                                \
        float4 _c = *(const float4*)(_s + 4);                                          \
        int _by = _kr * 256 + (((_kc ^ (_kr & 7)) & 15) << 4);                         \
        *(s16x8*)((char*)Kb + _by) = cvt8(_a, _c);                                     \
        int _hd = tid & 127, _kb = tid >> 7;                                           \
        const float* _sv = &F32V[p][_kb * 8 * HD_ + _hd];                              \
        union { s16x8 v; __bf16 hh[8]; } _u;                                           \
        _Pragma("unroll")                                                              \
        for (int _j = 0; _j < 8; ++_j) _u.hh[_j] = (__bf16)_sv[_j * HD_];              \
        int _vb = _hd * 64 + (((_kb ^ _hd ^ (_hd >> 2)) & 3) << 4);                    \
        *(s16x8*)((char*)Vtb + _vb) = _u.v;                                            \
    }

    // ---- prologue: tiles 0 and 1 in flight; convert tile 0 ----
    ISSUE_TILE(0, 0);
    ISSUE_TILE(1, 1);
    __syncthreads();          // vmcnt(0): both staged
    CVT_TILE(0);
    __syncthreads();          // bf16 tile 0 visible

    for (int t = 0; t < NTILE_; ++t) {
        const int p   = t & 1;
        const int kv0 = t * KB_;

        // async(t+2) -> staging buffer p (cvt(t) finished reading it, barrier passed)
        if (t + 2 < NTILE_) ISSUE_TILE(t + 2, p);

        // mask for tile t (plain loads; consumed after QK)
        f32x4 mk0 = *(const f32x4*)(maskrow + kv0 + l4 * 4);
        f32x4 mk1 = *(const f32x4*)(maskrow + kv0 + 16 + l4 * 4);

        // ---- S^T = K @ Q^T : st[mt] rows kv = mt*16 + l4*4 + r, cols q = l15 ----
        f32x4 st[2];
        st[0] = (f32x4){0.f, 0.f, 0.f, 0.f};
        st[1] = (f32x4){0.f, 0.f, 0.f, 0.f};
        #pragma unroll
        for (int mt = 0; mt < 2; ++mt) {
            int kr = mt * 16 + l15;
            #pragma unroll
            for (int kc = 0; kc < 4; ++kc) {
                s16x8 kf = *(const s16x8*)((const char*)Kb +
                            kr * 256 + ((((kc * 4 + l4) ^ (kr & 7)) & 15) << 4));
                st[mt] = MFMA16(kf, qf[kc], st[mt]);
            }
        }

        // ---- mask apply ----
        #pragma unroll
        for (int r = 0; r < 4; ++r) {
            st[0][r] = fmaf(mk0[r], st[0][r] + 10000.f, -10000.f);
            st[1][r] = fmaf(mk1[r], st[1][r] + 10000.f, -10000.f);
        }

        // ---- in-register softmax over kv (8 vals + 2 shfl) ----
        float rm = fmaxf(fmaxf(fmaxf(st[0][0], st[0][1]), fmaxf(st[0][2], st[0][3])),
                         fmaxf(fmaxf(st[1][0], st[1][1]), fmaxf(st[1][2], st[1][3])));
        rm = fmaxf(rm, __shfl_xor(rm, 16));
        rm = fmaxf(rm, __shfl_xor(rm, 32));

        if (!__all(rm <= mrun + 8.f)) {     // defer-max
            float nm = fmaxf(mrun, rm);
            float al = __expf(mrun - nm);
            mrun = nm;
            lrun *= al;
            float alr0 = __shfl(al, l4 * 4 + 0);
            float alr1 = __shfl(al, l4 * 4 + 1);
            float alr2 = __shfl(al, l4 * 4 + 2);
            float alr3 = __shfl(al, l4 * 4 + 3);
            #pragma unroll
            for (int nn = 0; nn < 8; ++nn) {
                acc[nn][0] *= alr0; acc[nn][1] *= alr1;
                acc[nn][2] *= alr2; acc[nn][3] *= alr3;
            }
        }

        float rs = 0.f;
        #pragma unroll
        for (int mt = 0; mt < 2; ++mt)
            #pragma unroll
            for (int r = 0; r < 4; ++r) {
                float pe = __expf(st[mt][r] - mrun);
                st[mt][r] = pe;
                rs += pe;
            }
        rs += __shfl_xor(rs, 16);
        rs += __shfl_xor(rs, 32);
        lrun += rs;

        // ---- pack P^T to bf16 ----
        union PK { int d[2]; __bf16 hh[4]; };
        PK pk0, pk1;
        pk0.hh[0]=(__bf16)st[0][0]; pk0.hh[1]=(__bf16)st[0][1];
        pk0.hh[2]=(__bf16)st[0][2]; pk0.hh[3]=(__bf16)st[0][3];
        pk1.hh[0]=(__bf16)st[1][0]; pk1.hh[1]=(__bf16)st[1][1];
        pk1.hh[2]=(__bf16)st[1][2]; pk1.hh[3]=(__bf16)st[1][3];

        // ---- assemble PV A-fragment: lane needs P[q=l15][kv=l4*8+j] ----
        const int srcA = (l4 & 1) * 32 + l15;
        const int srcB = srcA + 16;
        const int sel  = l4 >> 1;            // which mt
        s16x8 pa;
        {
            union { int d[4]; s16x8 v; } ua;
            int a0 = __shfl(pk0.d[0], srcA), a1 = __shfl(pk0.d[1], srcA);
            int b0 = __shfl(pk1.d[0], srcA), b1 = __shfl(pk1.d[1], srcA);
            int a2 = __shfl(pk0.d[0], srcB), a3 = __shfl(pk0.d[1], srcB);
            int b2 = __shfl(pk1.d[0], srcB), b3 = __shfl(pk1.d[1], srcB);
            ua.d[0] = sel ? b0 : a0; ua.d[1] = sel ? b1 : a1;
            ua.d[2] = sel ? b2 : a2; ua.d[3] = sel ? b3 : a3;
            pa = ua.v;
        }

        // ---- O += P @ V ----
        #pragma unroll
        for (int nn = 0; nn < 8; ++nn) {
            int hdv = nn * 16 + l15;
            s16x8 vf = *(const s16x8*)((const char*)Vtb +
                         hdv * 64 + (((l4 ^ hdv ^ (hdv >> 2)) & 3) << 4));
            acc[nn] = MFMA16(pa, vf, acc[nn]);
        }

        __syncthreads();                    // vmcnt(0)+lgkm drain: async(t+1) arrived
        if (t + 1 < NTILE_) CVT_TILE((t + 1) & 1);
        __syncthreads();                    // bf16 tile t+1 visible
    }

    // ---- epilogue ----
    float lr0 = __shfl(lrun, l4 * 4 + 0);
    float lr1 = __shfl(lrun, l4 * 4 + 1);
    float lr2 = __shfl(lrun, l4 * 4 + 2);
    float lr3 = __shfl(lrun, l4 * 4 + 3);
    float inv0 = 1.f / lr0, inv1 = 1.f / lr1, inv2 = 1.f / lr2, inv3 = 1.f / lr3;
    float* obase = ctx + (((size_t)(b * NH_ + h)) * SQ_ + q0 + w * 16 + l4 * 4) * HD_ + l15;
    #pragma unroll
    for (int nn = 0; nn < 8; ++nn) {
        obase[(size_t)0 * HD_ + nn * 16] = acc[nn][0] * inv0;
        obase[(size_t)1 * HD_ + nn * 16] = acc[nn][1] * inv1;
        obase[(size_t)2 * HD_ + nn * 16] = acc[nn][2] * inv2;
        obase[(size_t)3 * HD_ + nn * 16] = acc[nn][3] * inv3;
    }
}

// cache_kv: out[b][s][part][h][d] = (part ? v : k)[b][h][s][d]
__global__ void cachekv_kernel(const float* __restrict__ k, const float* __restrict__ v,
                               float* __restrict__ out)
{
    size_t i = ((size_t)blockIdx.x * 256 + threadIdx.x) * 4;
    unsigned f = (unsigned)i;
    unsigned d    = f & 127;
    unsigned hh   = (f >> 7) & 31;
    unsigned part = (f >> 12) & 1;
    unsigned s    = (f >> 13) & 511;
    unsigned bb   = f >> 22;
    const float* src = (part ? v : k) + (((size_t)(bb * 32u + hh)) * 512u + s) * 128u + d;
    *(float4*)(out + i) = *(const float4*)src;
}

extern "C" void kernel_launch(void* const* d_in, const int* in_sizes, int n_in,
                              void* d_out, int out_size, void* d_ws, size_t ws_size,
                              hipStream_t stream) {
    const float* q    = (const float*)d_in[0];
    const float* k    = (const float*)d_in[1];
    const float* v    = (const float*)d_in[2];
    const float* mask = (const float*)d_in[3];
    const float* mem  = (const float*)d_in[4];
    float* out = (float*)d_out;

    attn_kernel<<<dim3(B_ * NH_ * (SQ_ / QB_)), dim3(512), 0, stream>>>(q, k, v, mask, mem, out);

    const int ctx_elems = B_ * NH_ * SQ_ * HD_;                 // 8388608
    const int ckv_elems = B_ * SQ_ * 2 * NH_ * HD_;             // 16777216
    cachekv_kernel<<<dim3(ckv_elems / 4 / 256), dim3(256), 0, stream>>>(k, v, out + ctx_elems);
    (void)in_sizes; (void)n_in; (void)out_size; (void)d_ws; (void)ws_size;
}